// Round 19
// baseline (105.861 us; speedup 1.0000x reference)
//
#include <hip/hip_runtime.h>

#define T_SEQ 4096
#define NBATCH 4
#define CDIM 1024
#define NHEAD 64
#define SCALE (1.0f / 32.0f)
#define LOG2E 1.4426950408889634f
#define BT (NBATCH * T_SEQ)
#define NW 8             // waves per attn block (key-split factor)
#define WREG 8960        // per-wave LDS region bytes: o[32][68] f32 + m + l

typedef __bf16 bf16x8 __attribute__((ext_vector_type(8)));
typedef float f32x4 __attribute__((ext_vector_type(4)));
typedef float f32x16 __attribute__((ext_vector_type(16)));

__device__ __forceinline__ unsigned short f2bf(float f) {
  union { float f; unsigned u; } x;
  x.f = f;
  unsigned r = x.u + 0x7FFFu + ((x.u >> 16) & 1u);
  return (unsigned short)(r >> 16);
}

// RNE pack of two f32 -> one u32 of 2 bf16 (correctness verified R10-R16)
__device__ __forceinline__ unsigned cvt_pk(float lo, float hi) {
  unsigned d;
  asm("v_cvt_pk_bf16_f32 %0, %1, %2" : "=v"(d) : "v"(lo), "v"(hi));
  return d;
}

// lane-half swap, VALU pipe. Distinct-value operands only (R15 lesson).
__device__ __forceinline__ void swap32(unsigned& a, unsigned& b) {
  asm("v_permlane32_swap_b32 %0, %1" : "+v"(a), "+v"(b));
}

__device__ __forceinline__ f32x4 mfma16(bf16x8 a, bf16x8 b, f32x4 c) {
  return __builtin_amdgcn_mfma_f32_16x16x32_bf16(a, b, c, 0, 0, 0);
}

__device__ __forceinline__ f32x16 mfma32(bf16x8 a, bf16x8 b, f32x16 c) {
  return __builtin_amdgcn_mfma_f32_32x32x16_bf16(a, b, c, 0, 0, 0);
}

// ---------------------------------------------------------------------------
// Kernel 1: Wt[c][k] = W*(k, c%64) * (c<64 ? SCALE*log2e : 1), bf16.
// ---------------------------------------------------------------------------
__global__ void prep_w(const float* __restrict__ Wq, const float* __restrict__ Wk,
                       const float* __restrict__ Wv, unsigned short* __restrict__ Wt) {
  int c = blockIdx.x;
  const float* W = (c < 64) ? Wq : (c < 128) ? Wk : Wv;
  int cc = c & 63;
  float sc = (c < 64) ? (SCALE * LOG2E) : 1.0f;
  for (int k = threadIdx.x; k < CDIM; k += blockDim.x)
    Wt[c * CDIM + k] = f2bf(W[k * NHEAD + cc] * sc);
}

// ---------------------------------------------------------------------------
// Kernel 2: fused QKV projection — BARRIER-FREE PER-WAVE STREAM.
// R18 lesson (4th codegen-collapse instance): small per-wave work -> compiler
// minimizes VGPR -> hoisted loads serialize (VGPR 48, 58us, all pipes idle).
// Inverse design: 1024 blocks x 1 wave; wave owns 16 rows x ALL 192 cols
// (12 col-tiles, acc 48 VGPR), k marched in 32-chunks with explicit 2-stage
// ping-pong: compute chunk A while chunk B's {2 x-float4, 12 Wt b128} load.
// No LDS, no barriers; x read exactly once (64 MB, L3-resident). High reg
// pressure ON PURPOSE (~180 VGPR) + __launch_bounds__(64,1) (cap 512).
// A-frag: lane(c15,g) = x[rb+c15][k0+g*8..+7] via 4 cvt_pk.
// B-frag: Wt col=ct*16+c15, same k slice. D: col=c15, row=rb+4g+r.
// ---------------------------------------------------------------------------
__global__ __launch_bounds__(64, 1) void proj_qkv(
    const float* __restrict__ x, const unsigned short* __restrict__ Wt,
    unsigned short* __restrict__ qws, unsigned short* __restrict__ kws,
    unsigned short* __restrict__ vtws) {
  const int lane = threadIdx.x;
  const int c15 = lane & 15;
  const int g = lane >> 4;
  const int rb = blockIdx.x * 16;
  const float* xrow = x + (size_t)(rb + c15) * CDIM + g * 8;
  const unsigned short* wbase = Wt + (size_t)c15 * CDIM + g * 8;

  f32x4 acc[12];
#pragma unroll
  for (int ct = 0; ct < 12; ct++) acc[ct] = (f32x4){0.f, 0.f, 0.f, 0.f};

  float4 xa[2], xb[2];
  bf16x8 wa[12], wb[12];

  // prologue: chunk 0 -> A buffers
  xa[0] = *(const float4*)(xrow);
  xa[1] = *(const float4*)(xrow + 4);
#pragma unroll
  for (int ct = 0; ct < 12; ct++)
    wa[ct] = *(const bf16x8*)&wbase[(size_t)ct * 16 * CDIM];

  for (int ch = 0; ch < 32; ch += 2) {
    {  // issue chunk ch+1 -> B (always valid: ch <= 30)
      const int k1 = (ch + 1) * 32;
      xb[0] = *(const float4*)(xrow + k1);
      xb[1] = *(const float4*)(xrow + k1 + 4);
#pragma unroll
      for (int ct = 0; ct < 12; ct++)
        wb[ct] = *(const bf16x8*)&wbase[(size_t)ct * 16 * CDIM + k1];
    }
    {  // compute chunk ch from A
      union { unsigned u[4]; bf16x8 v; } av;
      av.u[0] = cvt_pk(xa[0].x, xa[0].y);
      av.u[1] = cvt_pk(xa[0].z, xa[0].w);
      av.u[2] = cvt_pk(xa[1].x, xa[1].y);
      av.u[3] = cvt_pk(xa[1].z, xa[1].w);
#pragma unroll
      for (int ct = 0; ct < 12; ct++)
        acc[ct] = mfma16(av.v, wa[ct], acc[ct]);
    }
    if (ch + 2 < 32) {  // issue chunk ch+2 -> A
      const int k2 = (ch + 2) * 32;
      xa[0] = *(const float4*)(xrow + k2);
      xa[1] = *(const float4*)(xrow + k2 + 4);
#pragma unroll
      for (int ct = 0; ct < 12; ct++)
        wa[ct] = *(const bf16x8*)&wbase[(size_t)ct * 16 * CDIM + k2];
    }
    {  // compute chunk ch+1 from B
      union { unsigned u[4]; bf16x8 v; } av;
      av.u[0] = cvt_pk(xb[0].x, xb[0].y);
      av.u[1] = cvt_pk(xb[0].z, xb[0].w);
      av.u[2] = cvt_pk(xb[1].x, xb[1].y);
      av.u[3] = cvt_pk(xb[1].z, xb[1].w);
#pragma unroll
      for (int ct = 0; ct < 12; ct++)
        acc[ct] = mfma16(av.v, wb[ct], acc[ct]);
    }
  }

#pragma unroll
  for (int ct = 0; ct < 12; ct++) {
    int col = ct * 16 + c15;
    for (int r = 0; r < 4; r++) {
      unsigned short v = f2bf(acc[ct][r]);
      int t = rb + 4 * g + r;
      if (col < 64)
        qws[(size_t)t * 64 + col] = v;
      else if (col < 128)
        kws[(size_t)t * 64 + (col - 64)] = v;
      else
        vtws[(size_t)(col - 128) * BT + t] = v;
    }
  }
}

// ---------------------------------------------------------------------------
// Kernel 3: causal flash attention — BYTE-IDENTICAL to R16 (41.3 us proven).
// 256 blocks x 8 waves, (512,2), in-block light/heavy halves (halves loop is
// REQUIRED: removing it flips codegen to a 56-VGPR serialized form, R14/R17).
// 32x32 MFMA; shfl_xor(32) max/sum; branchless rescale; cvt_pk + 4
// distinct-value permlane swaps -> PV B-frags; PV=mfma32(V,P).
// ---------------------------------------------------------------------------
__global__ __launch_bounds__(512, 2) void attn_fwd(
    const unsigned short* __restrict__ qws, const unsigned short* __restrict__ kws,
    const unsigned short* __restrict__ vtws, float* __restrict__ out) {
  __shared__ __align__(16) char smem[NW * WREG];  // 70 KiB
  const int tid = threadIdx.x;
  const int lane = tid & 63;
  const int w = tid >> 6;
  const int q31 = lane & 31;   // q-row within tile
  const int hi = lane >> 5;    // key-set selector (A/B)
  const int b = blockIdx.x >> 6;
  const int pi = blockIdx.x & 63;
  const size_t rowbase = (size_t)b * T_SEQ;
  char* wbase = smem + w * WREG;

  for (int half = 0; half < 2; ++half) {
    const int qt = half ? (127 - pi) : pi;
    const int qb = qt * 32;
    const int nsteps = qt + 1;  // 32-key steps

    bf16x8 qf[4];
    for (int h2 = 0; h2 < 4; h2++)
      qf[h2] = *(const bf16x8*)&qws[(rowbase + qb + q31) * 64 + h2 * 16 + hi * 8];

    f32x16 o[2];
    o[0] = (f32x16)0.f;
    o[1] = (f32x16)0.f;
    float mrow = -1e30f;
    float lrun = 0.f;

    for (int st = w; st < nsteps; st += NW) {
      const int kt = st * 32;
      bf16x8 ka[4];
      for (int h2 = 0; h2 < 4; h2++)
        ka[h2] =
            *(const bf16x8*)&kws[(rowbase + kt + q31) * 64 + h2 * 16 + hi * 8];
      bf16x8 va[2][2];
      for (int nt = 0; nt < 2; nt++)
        for (int ki = 0; ki < 2; ki++)
          va[nt][ki] = *(const bf16x8*)&vtws[(size_t)(nt * 32 + q31) * BT +
                                             rowbase + kt + ki * 16 + hi * 8];

      f32x16 s = (f32x16)0.f;
      for (int h2 = 0; h2 < 4; h2++) s = mfma32(ka[h2], qf[h2], s);

      float sv[16];
      for (int r = 0; r < 16; r++) sv[r] = s[r];

      if (st == nsteps - 1) {  // diagonal tile: causal mask (uniform branch)
        for (int r = 0; r < 16; r++) {
          int key = kt + (r & 3) + 8 * (r >> 2) + 4 * hi;
          if (key > qb + q31) sv[r] = -1e30f;
        }
      }

      float t01 = fmaxf(sv[0], sv[1]), t23 = fmaxf(sv[2], sv[3]);
      float t45 = fmaxf(sv[4], sv[5]), t67 = fmaxf(sv[6], sv[7]);
      float t89 = fmaxf(sv[8], sv[9]), tab = fmaxf(sv[10], sv[11]);
      float tcd = fmaxf(sv[12], sv[13]), tef = fmaxf(sv[14], sv[15]);
      float t = fmaxf(fmaxf(fmaxf(t01, t23), fmaxf(t45, t67)),
                      fmaxf(fmaxf(t89, tab), fmaxf(tcd, tef)));
      t = fmaxf(t, __shfl_xor(t, 32));

      float mn = fmaxf(mrow, t);
      float a = exp2f(mrow - mn);
      mrow = mn;
      o[0] *= a;
      o[1] *= a;
      lrun *= a;

      float p[16];
      for (int r = 0; r < 16; r++) p[r] = exp2f(sv[r] - mrow);

      float ssum = 0.f;
      for (int r = 0; r < 16; r++) ssum += p[r];
      lrun += ssum + __shfl_xor(ssum, 32);

      unsigned X[8];
      for (int jj = 0; jj < 8; jj++) X[jj] = cvt_pk(p[2 * jj], p[2 * jj + 1]);
      swap32(X[0], X[2]);
      swap32(X[1], X[3]);
      swap32(X[4], X[6]);
      swap32(X[5], X[7]);

      union { unsigned u[4]; bf16x8 v; } bf0, bf1;
      bf0.u[0] = X[0]; bf0.u[1] = X[1]; bf0.u[2] = X[2]; bf0.u[3] = X[3];
      bf1.u[0] = X[4]; bf1.u[1] = X[5]; bf1.u[2] = X[6]; bf1.u[3] = X[7];

      for (int nt = 0; nt < 2; nt++) {
        o[nt] = mfma32(va[nt][0], bf0.v, o[nt]);
        o[nt] = mfma32(va[nt][1], bf1.v, o[nt]);
      }
    }

    // ---- per-wave partials; o stride 68 f32 ----
    float* ow = (float*)wbase;
    float* mw = (float*)(wbase + 8704);
    float* lw = (float*)(wbase + 8832);
    for (int nt = 0; nt < 2; nt++)
      for (int r = 0; r < 16; r++) {
        int d = nt * 32 + (r & 3) + 8 * (r >> 2) + 4 * hi;
        ow[q31 * 68 + d] = o[nt][r];
      }
    if (hi == 0) {
      mw[q31] = mrow;
      lw[q31] = lrun;
    }
    __syncthreads();

    // ---- LSE-merge across 8 waves (log2 domain): 512 thr x 4 = 32x64 ----
    for (int i = 0; i < 4; i++) {
      int e = tid + i * 512;
      int row = e >> 6;
      int d = e & 63;
      float M = -1e30f;
      for (int ww = 0; ww < NW; ww++)
        M = fmaxf(M, ((const float*)(smem + ww * WREG + 8704))[row]);
      float L = 0.f, O = 0.f;
      for (int ww = 0; ww < NW; ww++) {
        float mv = ((const float*)(smem + ww * WREG + 8704))[row];
        float f = exp2f(mv - M);
        L += f * ((const float*)(smem + ww * WREG + 8832))[row];
        O += f * ((const float*)(smem + ww * WREG))[row * 68 + d];
      }
      out[(rowbase + qb + row) * 64 + d] = O / L;
    }
    __syncthreads();  // merge reads done before next half reuses partials
  }
}

// ---------------------------------------------------------------------------
extern "C" void kernel_launch(void* const* d_in, const int* in_sizes, int n_in,
                              void* d_out, int out_size, void* d_ws, size_t ws_size,
                              hipStream_t stream) {
  const float* x = (const float*)d_in[0];
  const float* Wq = (const float*)d_in[1];
  const float* Wk = (const float*)d_in[2];
  const float* Wv = (const float*)d_in[3];
  float* out = (float*)d_out;

  char* ws = (char*)d_ws;
  unsigned short* Wt = (unsigned short*)(ws);                          // 384 KB
  unsigned short* qws = (unsigned short*)(ws + 393216);                // 2 MB
  unsigned short* kws = (unsigned short*)(ws + 393216 + 2097152);      // 2 MB
  unsigned short* vtws = (unsigned short*)(ws + 393216 + 2 * 2097152); // 2 MB

  prep_w<<<dim3(192), dim3(256), 0, stream>>>(Wq, Wk, Wv, Wt);
  proj_qkv<<<dim3(1024), dim3(64), 0, stream>>>(x, Wt, qws, kws, vtws);
  attn_fwd<<<dim3(256), dim3(512), 0, stream>>>(qws, kws, vtws, out);
}

// Round 20
// 79.768 us; speedup vs baseline: 1.3271x; 1.3271x over previous
//
#include <hip/hip_runtime.h>

#define T_SEQ 4096
#define NBATCH 4
#define CDIM 1024
#define NHEAD 64
#define SCALE (1.0f / 32.0f)
#define LOG2E 1.4426950408889634f
#define BT (NBATCH * T_SEQ)
#define NW 8             // waves per attn block (key-split factor)
#define WREG 8960        // per-wave LDS region bytes: o[32][68] f32 + m + l

typedef __bf16 bf16x8 __attribute__((ext_vector_type(8)));
typedef float f32x4 __attribute__((ext_vector_type(4)));
typedef float f32x16 __attribute__((ext_vector_type(16)));

__device__ __forceinline__ unsigned short f2bf(float f) {
  union { float f; unsigned u; } x;
  x.f = f;
  unsigned r = x.u + 0x7FFFu + ((x.u >> 16) & 1u);
  return (unsigned short)(r >> 16);
}

// RNE pack of two f32 -> one u32 of 2 bf16 (correctness verified R10-R16)
__device__ __forceinline__ unsigned cvt_pk(float lo, float hi) {
  unsigned d;
  asm("v_cvt_pk_bf16_f32 %0, %1, %2" : "=v"(d) : "v"(lo), "v"(hi));
  return d;
}

// lane-half swap, VALU pipe. Distinct-value operands only (R15 lesson).
__device__ __forceinline__ void swap32(unsigned& a, unsigned& b) {
  asm("v_permlane32_swap_b32 %0, %1" : "+v"(a), "+v"(b));
}

__device__ __forceinline__ f32x4 mfma16(bf16x8 a, bf16x8 b, f32x4 c) {
  return __builtin_amdgcn_mfma_f32_16x16x32_bf16(a, b, c, 0, 0, 0);
}

__device__ __forceinline__ f32x16 mfma32(bf16x8 a, bf16x8 b, f32x16 c) {
  return __builtin_amdgcn_mfma_f32_32x32x16_bf16(a, b, c, 0, 0, 0);
}

// ---------------------------------------------------------------------------
// Kernel 1: Wt[c][k] = W*(k, c%64) * (c<64 ? SCALE*log2e : 1), bf16.
// R19 fix: LDS-tile transpose so BOTH global sides are coalesced (the old
// version read W at stride-256B per lane). 48 blocks = 3 matrices x 16
// k-tiles of 64; read 64x64 f32 tile coalesced (lane = h), transpose via
// wlds[64][65] (pad -> conflict-free), write 64 consecutive k per c (128B).
// ---------------------------------------------------------------------------
__global__ __launch_bounds__(256) void prep_w(
    const float* __restrict__ Wq, const float* __restrict__ Wk,
    const float* __restrict__ Wv, unsigned short* __restrict__ Wt) {
  __shared__ float wlds[64][65];
  const int m = blockIdx.x / 16;       // matrix: 0=q, 1=k, 2=v
  const int kt = blockIdx.x % 16;      // k-tile (64 rows of W)
  const float* W = (m == 0) ? Wq : (m == 1) ? Wk : Wv;
  const float s = (m == 0) ? (SCALE * LOG2E) : 1.0f;
  const int tid = threadIdx.x;
  const int la = tid & 63;             // read: h index; write: k index
  const int gr = tid >> 6;             // 4 groups of 64 lanes

  for (int i = 0; i < 16; i++) {
    int kl = gr * 16 + i;              // k within tile
    wlds[kl][la] = W[(size_t)(kt * 64 + kl) * NHEAD + la];
  }
  __syncthreads();
  for (int i = 0; i < 16; i++) {
    int cl = gr * 16 + i;              // c (head col) within tile
    Wt[(size_t)(m * 64 + cl) * CDIM + kt * 64 + la] = f2bf(wlds[la][cl] * s);
  }
}

// ---------------------------------------------------------------------------
// Kernel 2: fused QKV projection — BYTE-IDENTICAL to R16 (proven in the
// 79.8us run). M-tile 32, 512 blocks x 4 waves, LDS double-buffer (one
// barrier/iter), 12 Wt B-frag loads hoisted & in flight.
// proj restructure attempts R17/R18/R19 (M16 grids, 1-wave stream) all
// collapsed codegen (VGPR 48-80, serialized loads, 58-70us) — per-wave work
// below this threshold makes hipcc minimize registers and serialize.
// ---------------------------------------------------------------------------
__global__ __launch_bounds__(256) void proj_qkv(
    const float* __restrict__ x, const unsigned short* __restrict__ Wt,
    unsigned short* __restrict__ qws, unsigned short* __restrict__ kws,
    unsigned short* __restrict__ vtws) {
  __shared__ unsigned short xlds[2][32][136];  // 2 x (128 bf16 + 8 pad)
  const int tid = threadIdx.x;
  const int lane = tid & 63;
  const int w = tid >> 6;
  const int g = lane >> 4;
  const int c15 = lane & 15;
  const int rb = blockIdx.x * 32;

  f32x4 acc[2][3];
  for (int i = 0; i < 2; i++)
    for (int j = 0; j < 3; j++) acc[i][j] = (f32x4){0.f, 0.f, 0.f, 0.f};

  const int sr = tid >> 3;         // staging row 0..31
  const int scc = (tid & 7) * 16;  // staging col base
  const float* xrow = x + (size_t)(rb + sr) * CDIM + scc;

  {
    float4 cur[4];
    for (int i = 0; i < 4; i++) cur[i] = *(const float4*)(xrow + i * 4);
    unsigned short pk[16];
    for (int i = 0; i < 4; i++) {
      pk[i * 4 + 0] = f2bf(cur[i].x);
      pk[i * 4 + 1] = f2bf(cur[i].y);
      pk[i * 4 + 2] = f2bf(cur[i].z);
      pk[i * 4 + 3] = f2bf(cur[i].w);
    }
    *(bf16x8*)&xlds[0][sr][scc] = *(bf16x8*)&pk[0];
    *(bf16x8*)&xlds[0][sr][scc + 8] = *(bf16x8*)&pk[8];
  }
  __syncthreads();

  int pb = 0;
  for (int k0 = 0; k0 < CDIM; k0 += 128) {
    const bool more = (k0 + 128 < CDIM);
    float4 nxt[4];
    if (more)
      for (int i = 0; i < 4; i++)
        nxt[i] = *(const float4*)(xrow + k0 + 128 + i * 4);

    bf16x8 wfrag[4][3];
    for (int kk = 0; kk < 4; kk++)
      for (int bn = 0; bn < 3; bn++) {
        int col = w * 48 + bn * 16 + c15;
        wfrag[kk][bn] =
            *(const bf16x8*)&Wt[(size_t)col * CDIM + k0 + kk * 32 + g * 8];
      }

    for (int kk = 0; kk < 4; kk++) {
      bf16x8 a[2];
      for (int mt = 0; mt < 2; mt++)
        a[mt] = *(bf16x8*)&xlds[pb][mt * 16 + c15][kk * 32 + g * 8];
      for (int bn = 0; bn < 3; bn++)
        for (int mt = 0; mt < 2; mt++)
          acc[mt][bn] = mfma16(a[mt], wfrag[kk][bn], acc[mt][bn]);
    }

    if (more) {
      unsigned short pk[16];
      for (int i = 0; i < 4; i++) {
        pk[i * 4 + 0] = f2bf(nxt[i].x);
        pk[i * 4 + 1] = f2bf(nxt[i].y);
        pk[i * 4 + 2] = f2bf(nxt[i].z);
        pk[i * 4 + 3] = f2bf(nxt[i].w);
      }
      *(bf16x8*)&xlds[pb ^ 1][sr][scc] = *(bf16x8*)&pk[0];
      *(bf16x8*)&xlds[pb ^ 1][sr][scc + 8] = *(bf16x8*)&pk[8];
    }
    __syncthreads();
    pb ^= 1;
  }

  for (int mt = 0; mt < 2; mt++)
    for (int bn = 0; bn < 3; bn++) {
      int col = w * 48 + bn * 16 + c15;
      int row0 = rb + mt * 16 + 4 * g;
      for (int r = 0; r < 4; r++) {
        unsigned short v = f2bf(acc[mt][bn][r]);
        int t = row0 + r;
        if (col < 64)
          qws[(size_t)t * 64 + col] = v;
        else if (col < 128)
          kws[(size_t)t * 64 + (col - 64)] = v;
        else
          vtws[(size_t)(col - 128) * BT + t] = v;
      }
    }
}

// ---------------------------------------------------------------------------
// Kernel 3: causal flash attention — BYTE-IDENTICAL to R16 (41.3 us proven).
// 256 blocks x 8 waves, (512,2), in-block light/heavy halves (halves loop is
// REQUIRED: removing it flips codegen to a 56-VGPR serialized form, R14/R17).
// 32x32 MFMA; shfl_xor(32) max/sum; branchless rescale; cvt_pk + 4
// distinct-value permlane swaps -> PV B-frags; PV=mfma32(V,P).
// ---------------------------------------------------------------------------
__global__ __launch_bounds__(512, 2) void attn_fwd(
    const unsigned short* __restrict__ qws, const unsigned short* __restrict__ kws,
    const unsigned short* __restrict__ vtws, float* __restrict__ out) {
  __shared__ __align__(16) char smem[NW * WREG];  // 70 KiB
  const int tid = threadIdx.x;
  const int lane = tid & 63;
  const int w = tid >> 6;
  const int q31 = lane & 31;   // q-row within tile
  const int hi = lane >> 5;    // key-set selector (A/B)
  const int b = blockIdx.x >> 6;
  const int pi = blockIdx.x & 63;
  const size_t rowbase = (size_t)b * T_SEQ;
  char* wbase = smem + w * WREG;

  for (int half = 0; half < 2; ++half) {
    const int qt = half ? (127 - pi) : pi;
    const int qb = qt * 32;
    const int nsteps = qt + 1;  // 32-key steps

    bf16x8 qf[4];
    for (int h2 = 0; h2 < 4; h2++)
      qf[h2] = *(const bf16x8*)&qws[(rowbase + qb + q31) * 64 + h2 * 16 + hi * 8];

    f32x16 o[2];
    o[0] = (f32x16)0.f;
    o[1] = (f32x16)0.f;
    float mrow = -1e30f;
    float lrun = 0.f;

    for (int st = w; st < nsteps; st += NW) {
      const int kt = st * 32;
      bf16x8 ka[4];
      for (int h2 = 0; h2 < 4; h2++)
        ka[h2] =
            *(const bf16x8*)&kws[(rowbase + kt + q31) * 64 + h2 * 16 + hi * 8];
      bf16x8 va[2][2];
      for (int nt = 0; nt < 2; nt++)
        for (int ki = 0; ki < 2; ki++)
          va[nt][ki] = *(const bf16x8*)&vtws[(size_t)(nt * 32 + q31) * BT +
                                             rowbase + kt + ki * 16 + hi * 8];

      f32x16 s = (f32x16)0.f;
      for (int h2 = 0; h2 < 4; h2++) s = mfma32(ka[h2], qf[h2], s);

      float sv[16];
      for (int r = 0; r < 16; r++) sv[r] = s[r];

      if (st == nsteps - 1) {  // diagonal tile: causal mask (uniform branch)
        for (int r = 0; r < 16; r++) {
          int key = kt + (r & 3) + 8 * (r >> 2) + 4 * hi;
          if (key > qb + q31) sv[r] = -1e30f;
        }
      }

      float t01 = fmaxf(sv[0], sv[1]), t23 = fmaxf(sv[2], sv[3]);
      float t45 = fmaxf(sv[4], sv[5]), t67 = fmaxf(sv[6], sv[7]);
      float t89 = fmaxf(sv[8], sv[9]), tab = fmaxf(sv[10], sv[11]);
      float tcd = fmaxf(sv[12], sv[13]), tef = fmaxf(sv[14], sv[15]);
      float t = fmaxf(fmaxf(fmaxf(t01, t23), fmaxf(t45, t67)),
                      fmaxf(fmaxf(t89, tab), fmaxf(tcd, tef)));
      t = fmaxf(t, __shfl_xor(t, 32));

      float mn = fmaxf(mrow, t);
      float a = exp2f(mrow - mn);
      mrow = mn;
      o[0] *= a;
      o[1] *= a;
      lrun *= a;

      float p[16];
      for (int r = 0; r < 16; r++) p[r] = exp2f(sv[r] - mrow);

      float ssum = 0.f;
      for (int r = 0; r < 16; r++) ssum += p[r];
      lrun += ssum + __shfl_xor(ssum, 32);

      unsigned X[8];
      for (int jj = 0; jj < 8; jj++) X[jj] = cvt_pk(p[2 * jj], p[2 * jj + 1]);
      swap32(X[0], X[2]);
      swap32(X[1], X[3]);
      swap32(X[4], X[6]);
      swap32(X[5], X[7]);

      union { unsigned u[4]; bf16x8 v; } bf0, bf1;
      bf0.u[0] = X[0]; bf0.u[1] = X[1]; bf0.u[2] = X[2]; bf0.u[3] = X[3];
      bf1.u[0] = X[4]; bf1.u[1] = X[5]; bf1.u[2] = X[6]; bf1.u[3] = X[7];

      for (int nt = 0; nt < 2; nt++) {
        o[nt] = mfma32(va[nt][0], bf0.v, o[nt]);
        o[nt] = mfma32(va[nt][1], bf1.v, o[nt]);
      }
    }

    // ---- per-wave partials; o stride 68 f32 ----
    float* ow = (float*)wbase;
    float* mw = (float*)(wbase + 8704);
    float* lw = (float*)(wbase + 8832);
    for (int nt = 0; nt < 2; nt++)
      for (int r = 0; r < 16; r++) {
        int d = nt * 32 + (r & 3) + 8 * (r >> 2) + 4 * hi;
        ow[q31 * 68 + d] = o[nt][r];
      }
    if (hi == 0) {
      mw[q31] = mrow;
      lw[q31] = lrun;
    }
    __syncthreads();

    // ---- LSE-merge across 8 waves (log2 domain): 512 thr x 4 = 32x64 ----
    for (int i = 0; i < 4; i++) {
      int e = tid + i * 512;
      int row = e >> 6;
      int d = e & 63;
      float M = -1e30f;
      for (int ww = 0; ww < NW; ww++)
        M = fmaxf(M, ((const float*)(smem + ww * WREG + 8704))[row]);
      float L = 0.f, O = 0.f;
      for (int ww = 0; ww < NW; ww++) {
        float mv = ((const float*)(smem + ww * WREG + 8704))[row];
        float f = exp2f(mv - M);
        L += f * ((const float*)(smem + ww * WREG + 8832))[row];
        O += f * ((const float*)(smem + ww * WREG))[row * 68 + d];
      }
      out[(rowbase + qb + row) * 64 + d] = O / L;
    }
    __syncthreads();  // merge reads done before next half reuses partials
  }
}

// ---------------------------------------------------------------------------
extern "C" void kernel_launch(void* const* d_in, const int* in_sizes, int n_in,
                              void* d_out, int out_size, void* d_ws, size_t ws_size,
                              hipStream_t stream) {
  const float* x = (const float*)d_in[0];
  const float* Wq = (const float*)d_in[1];
  const float* Wk = (const float*)d_in[2];
  const float* Wv = (const float*)d_in[3];
  float* out = (float*)d_out;

  char* ws = (char*)d_ws;
  unsigned short* Wt = (unsigned short*)(ws);                          // 384 KB
  unsigned short* qws = (unsigned short*)(ws + 393216);                // 2 MB
  unsigned short* kws = (unsigned short*)(ws + 393216 + 2097152);      // 2 MB
  unsigned short* vtws = (unsigned short*)(ws + 393216 + 2 * 2097152); // 2 MB

  prep_w<<<dim3(48), dim3(256), 0, stream>>>(Wq, Wk, Wv, Wt);
  proj_qkv<<<dim3(512), dim3(256), 0, stream>>>(x, Wt, qws, kws, vtws);
  attn_fwd<<<dim3(256), dim3(512), 0, stream>>>(qws, kws, vtws, out);
}

// Round 21
// 79.004 us; speedup vs baseline: 1.3399x; 1.0097x over previous
//
#include <hip/hip_runtime.h>

#define T_SEQ 4096
#define NBATCH 4
#define CDIM 1024
#define NHEAD 64
#define SCALE (1.0f / 32.0f)
#define LOG2E 1.4426950408889634f
#define BT (NBATCH * T_SEQ)
#define NW 8             // waves per attn block (key-split factor)
#define WREG 8960        // per-wave LDS region bytes: o[32][68] f32 + m + l

typedef __bf16 bf16x8 __attribute__((ext_vector_type(8)));
typedef float f32x4 __attribute__((ext_vector_type(4)));
typedef float f32x16 __attribute__((ext_vector_type(16)));

__device__ __forceinline__ unsigned short f2bf(float f) {
  union { float f; unsigned u; } x;
  x.f = f;
  unsigned r = x.u + 0x7FFFu + ((x.u >> 16) & 1u);
  return (unsigned short)(r >> 16);
}

// RNE pack of two f32 -> one u32 of 2 bf16 (correctness verified R10-R20)
__device__ __forceinline__ unsigned cvt_pk(float lo, float hi) {
  unsigned d;
  asm("v_cvt_pk_bf16_f32 %0, %1, %2" : "=v"(d) : "v"(lo), "v"(hi));
  return d;
}

// lane-half swap, VALU pipe. Distinct-value operands only (R15 lesson).
__device__ __forceinline__ void swap32(unsigned& a, unsigned& b) {
  asm("v_permlane32_swap_b32 %0, %1" : "+v"(a), "+v"(b));
}

__device__ __forceinline__ f32x4 mfma16(bf16x8 a, bf16x8 b, f32x4 c) {
  return __builtin_amdgcn_mfma_f32_16x16x32_bf16(a, b, c, 0, 0, 0);
}

__device__ __forceinline__ f32x16 mfma32(bf16x8 a, bf16x8 b, f32x16 c) {
  return __builtin_amdgcn_mfma_f32_32x32x16_bf16(a, b, c, 0, 0, 0);
}

// ---------------------------------------------------------------------------
// Kernel 1: Wt transpose-prep (R19-verified, coalesced both sides).
// ---------------------------------------------------------------------------
__global__ __launch_bounds__(256) void prep_w(
    const float* __restrict__ Wq, const float* __restrict__ Wk,
    const float* __restrict__ Wv, unsigned short* __restrict__ Wt) {
  __shared__ float wlds[64][65];
  const int m = blockIdx.x / 16;       // matrix: 0=q, 1=k, 2=v
  const int kt = blockIdx.x % 16;      // k-tile (64 rows of W)
  const float* W = (m == 0) ? Wq : (m == 1) ? Wk : Wv;
  const float s = (m == 0) ? (SCALE * LOG2E) : 1.0f;
  const int tid = threadIdx.x;
  const int la = tid & 63;
  const int gr = tid >> 6;

  for (int i = 0; i < 16; i++) {
    int kl = gr * 16 + i;
    wlds[kl][la] = W[(size_t)(kt * 64 + kl) * NHEAD + la];
  }
  __syncthreads();
  for (int i = 0; i < 16; i++) {
    int cl = gr * 16 + i;
    Wt[(size_t)(m * 64 + cl) * CDIM + kt * 64 + la] = f2bf(wlds[la][cl] * s);
  }
}

// ---------------------------------------------------------------------------
// Kernel 2: fused QKV projection — BYTE-IDENTICAL to R16 (proven).
// M-tile 32, 512 blocks x 4 waves, LDS double-buffer, hoisted Wt loads.
// (All 5 restructures R17-R19 collapsed codegen; do not shrink per-wave work.)
// ---------------------------------------------------------------------------
__global__ __launch_bounds__(256) void proj_qkv(
    const float* __restrict__ x, const unsigned short* __restrict__ Wt,
    unsigned short* __restrict__ qws, unsigned short* __restrict__ kws,
    unsigned short* __restrict__ vtws) {
  __shared__ unsigned short xlds[2][32][136];
  const int tid = threadIdx.x;
  const int lane = tid & 63;
  const int w = tid >> 6;
  const int g = lane >> 4;
  const int c15 = lane & 15;
  const int rb = blockIdx.x * 32;

  f32x4 acc[2][3];
  for (int i = 0; i < 2; i++)
    for (int j = 0; j < 3; j++) acc[i][j] = (f32x4){0.f, 0.f, 0.f, 0.f};

  const int sr = tid >> 3;
  const int scc = (tid & 7) * 16;
  const float* xrow = x + (size_t)(rb + sr) * CDIM + scc;

  {
    float4 cur[4];
    for (int i = 0; i < 4; i++) cur[i] = *(const float4*)(xrow + i * 4);
    unsigned short pk[16];
    for (int i = 0; i < 4; i++) {
      pk[i * 4 + 0] = f2bf(cur[i].x);
      pk[i * 4 + 1] = f2bf(cur[i].y);
      pk[i * 4 + 2] = f2bf(cur[i].z);
      pk[i * 4 + 3] = f2bf(cur[i].w);
    }
    *(bf16x8*)&xlds[0][sr][scc] = *(bf16x8*)&pk[0];
    *(bf16x8*)&xlds[0][sr][scc + 8] = *(bf16x8*)&pk[8];
  }
  __syncthreads();

  int pb = 0;
  for (int k0 = 0; k0 < CDIM; k0 += 128) {
    const bool more = (k0 + 128 < CDIM);
    float4 nxt[4];
    if (more)
      for (int i = 0; i < 4; i++)
        nxt[i] = *(const float4*)(xrow + k0 + 128 + i * 4);

    bf16x8 wfrag[4][3];
    for (int kk = 0; kk < 4; kk++)
      for (int bn = 0; bn < 3; bn++) {
        int col = w * 48 + bn * 16 + c15;
        wfrag[kk][bn] =
            *(const bf16x8*)&Wt[(size_t)col * CDIM + k0 + kk * 32 + g * 8];
      }

    for (int kk = 0; kk < 4; kk++) {
      bf16x8 a[2];
      for (int mt = 0; mt < 2; mt++)
        a[mt] = *(bf16x8*)&xlds[pb][mt * 16 + c15][kk * 32 + g * 8];
      for (int bn = 0; bn < 3; bn++)
        for (int mt = 0; mt < 2; mt++)
          acc[mt][bn] = mfma16(a[mt], wfrag[kk][bn], acc[mt][bn]);
    }

    if (more) {
      unsigned short pk[16];
      for (int i = 0; i < 4; i++) {
        pk[i * 4 + 0] = f2bf(nxt[i].x);
        pk[i * 4 + 1] = f2bf(nxt[i].y);
        pk[i * 4 + 2] = f2bf(nxt[i].z);
        pk[i * 4 + 3] = f2bf(nxt[i].w);
      }
      *(bf16x8*)&xlds[pb ^ 1][sr][scc] = *(bf16x8*)&pk[0];
      *(bf16x8*)&xlds[pb ^ 1][sr][scc + 8] = *(bf16x8*)&pk[8];
    }
    __syncthreads();
    pb ^= 1;
  }

  for (int mt = 0; mt < 2; mt++)
    for (int bn = 0; bn < 3; bn++) {
      int col = w * 48 + bn * 16 + c15;
      int row0 = rb + mt * 16 + 4 * g;
      for (int r = 0; r < 4; r++) {
        unsigned short v = f2bf(acc[mt][bn][r]);
        int t = row0 + r;
        if (col < 64)
          qws[(size_t)t * 64 + col] = v;
        else if (col < 128)
          kws[(size_t)t * 64 + (col - 64)] = v;
        else
          vtws[(size_t)(col - 128) * BT + t] = v;
      }
    }
}

// ---------------------------------------------------------------------------
// Kernel 3: causal flash attention — CONCURRENT light/heavy q-tiles.
// R20 state: attn latency-bound at 2 waves/SIMD (MfmaUtil 7, VALU 34, HBM 5);
// TLP is reg-capped. This round: each wave processes BOTH its q-tiles
// (qt0=pi light, qt1=127-pi heavy) in ONE loop over the heavy tile's steps,
// with a SHARED K/V load (light's keys are a subset of heavy's). Two
// independent softmax chains per step -> ILP the scheduler can interleave;
// ~25% fewer K/V loads. State doubles (~190 VGPR) — the historically SAFE
// codegen direction (all collapses came from SHRINKING per-wave work).
// Step body byte-equivalent to R16's verified math (32x32 MFMA, shfl_xor(32)
// max/sum, branchless rescale, cvt_pk + distinct-value permlane swaps).
// Two sequential epilogues reuse the per-wave WREG region. Waves with no
// light steps contribute 0 in the merge (mrow=-1e30 -> f=0, lrun=0).
// ---------------------------------------------------------------------------
__global__ __launch_bounds__(512, 2) void attn_fwd(
    const unsigned short* __restrict__ qws, const unsigned short* __restrict__ kws,
    const unsigned short* __restrict__ vtws, float* __restrict__ out) {
  __shared__ __align__(16) char smem[NW * WREG];  // 70 KiB
  const int tid = threadIdx.x;
  const int lane = tid & 63;
  const int w = tid >> 6;
  const int q31 = lane & 31;   // q-row within tile
  const int hi = lane >> 5;    // key-set selector (A/B)
  const int b = blockIdx.x >> 6;
  const int pi = blockIdx.x & 63;
  const size_t rowbase = (size_t)b * T_SEQ;
  char* wbase = smem + w * WREG;

  const int qb0 = pi * 32;            // light tile
  const int qb1 = (127 - pi) * 32;    // heavy tile
  const int n0 = pi + 1;              // light steps
  const int n1 = 128 - pi;            // heavy steps (n0 <= n1)

  bf16x8 qf0[4], qf1[4];
  for (int h2 = 0; h2 < 4; h2++) {
    qf0[h2] =
        *(const bf16x8*)&qws[(rowbase + qb0 + q31) * 64 + h2 * 16 + hi * 8];
    qf1[h2] =
        *(const bf16x8*)&qws[(rowbase + qb1 + q31) * 64 + h2 * 16 + hi * 8];
  }

  f32x16 o0[2], o1[2];
  o0[0] = (f32x16)0.f; o0[1] = (f32x16)0.f;
  o1[0] = (f32x16)0.f; o1[1] = (f32x16)0.f;
  float m0 = -1e30f, m1 = -1e30f;
  float l0 = 0.f, l1 = 0.f;

  // one softmax+PV step for one tile (R16-verified math)
  auto STEP = [&](int st, int kt, int qb_, int nst, bf16x8 (&qf_)[4],
                  f32x16 (&o_)[2], float& mrow_, float& lrun_,
                  bf16x8 (&ka)[4], bf16x8 (&va)[2][2]) {
    f32x16 s = (f32x16)0.f;
    for (int h2 = 0; h2 < 4; h2++) s = mfma32(ka[h2], qf_[h2], s);

    float sv[16];
    for (int r = 0; r < 16; r++) sv[r] = s[r];
    if (st == nst - 1) {  // diagonal tile: causal mask (uniform branch)
      for (int r = 0; r < 16; r++) {
        int key = kt + (r & 3) + 8 * (r >> 2) + 4 * hi;
        if (key > qb_ + q31) sv[r] = -1e30f;
      }
    }

    float t01 = fmaxf(sv[0], sv[1]), t23 = fmaxf(sv[2], sv[3]);
    float t45 = fmaxf(sv[4], sv[5]), t67 = fmaxf(sv[6], sv[7]);
    float t89 = fmaxf(sv[8], sv[9]), tab = fmaxf(sv[10], sv[11]);
    float tcd = fmaxf(sv[12], sv[13]), tef = fmaxf(sv[14], sv[15]);
    float t = fmaxf(fmaxf(fmaxf(t01, t23), fmaxf(t45, t67)),
                    fmaxf(fmaxf(t89, tab), fmaxf(tcd, tef)));
    t = fmaxf(t, __shfl_xor(t, 32));

    float mn = fmaxf(mrow_, t);
    float a = exp2f(mrow_ - mn);
    mrow_ = mn;
    o_[0] *= a;
    o_[1] *= a;
    lrun_ *= a;

    float p[16];
    for (int r = 0; r < 16; r++) p[r] = exp2f(sv[r] - mrow_);

    float ssum = 0.f;
    for (int r = 0; r < 16; r++) ssum += p[r];
    lrun_ += ssum + __shfl_xor(ssum, 32);

    unsigned X[8];
    for (int jj = 0; jj < 8; jj++) X[jj] = cvt_pk(p[2 * jj], p[2 * jj + 1]);
    swap32(X[0], X[2]);
    swap32(X[1], X[3]);
    swap32(X[4], X[6]);
    swap32(X[5], X[7]);

    union { unsigned u[4]; bf16x8 v; } bf0, bf1;
    bf0.u[0] = X[0]; bf0.u[1] = X[1]; bf0.u[2] = X[2]; bf0.u[3] = X[3];
    bf1.u[0] = X[4]; bf1.u[1] = X[5]; bf1.u[2] = X[6]; bf1.u[3] = X[7];

    for (int nt = 0; nt < 2; nt++) {
      o_[nt] = mfma32(va[nt][0], bf0.v, o_[nt]);
      o_[nt] = mfma32(va[nt][1], bf1.v, o_[nt]);
    }
  };

  for (int st = w; st < n1; st += NW) {
    const int kt = st * 32;
    // shared K/V load for both tiles
    bf16x8 ka[4];
    for (int h2 = 0; h2 < 4; h2++)
      ka[h2] = *(const bf16x8*)&kws[(rowbase + kt + q31) * 64 + h2 * 16 + hi * 8];
    bf16x8 va[2][2];
    for (int nt = 0; nt < 2; nt++)
      for (int ki = 0; ki < 2; ki++)
        va[nt][ki] = *(const bf16x8*)&vtws[(size_t)(nt * 32 + q31) * BT +
                                           rowbase + kt + ki * 16 + hi * 8];

    STEP(st, kt, qb1, n1, qf1, o1, m1, l1, ka, va);       // heavy: always
    if (st < n0)                                          // light: subset
      STEP(st, kt, qb0, n0, qf0, o0, m0, l0, ka, va);
  }

  // ---- epilogue: tile1 then tile0, reusing the same WREG region ----
  auto EPI = [&](int qb_, f32x16 (&o_)[2], float mrow_, float lrun_) {
    float* ow = (float*)wbase;
    float* mw = (float*)(wbase + 8704);
    float* lw = (float*)(wbase + 8832);
    for (int nt = 0; nt < 2; nt++)
      for (int r = 0; r < 16; r++) {
        int d = nt * 32 + (r & 3) + 8 * (r >> 2) + 4 * hi;
        ow[q31 * 68 + d] = o_[nt][r];
      }
    if (hi == 0) {
      mw[q31] = mrow_;
      lw[q31] = lrun_;
    }
    __syncthreads();

    for (int i = 0; i < 4; i++) {
      int e = tid + i * 512;
      int row = e >> 6;
      int d = e & 63;
      float M = -1e30f;
      for (int ww = 0; ww < NW; ww++)
        M = fmaxf(M, ((const float*)(smem + ww * WREG + 8704))[row]);
      float L = 0.f, O = 0.f;
      for (int ww = 0; ww < NW; ww++) {
        float mv = ((const float*)(smem + ww * WREG + 8704))[row];
        float f = exp2f(mv - M);
        L += f * ((const float*)(smem + ww * WREG + 8832))[row];
        O += f * ((const float*)(smem + ww * WREG))[row * 68 + d];
      }
      out[(rowbase + qb_ + row) * 64 + d] = O / L;
    }
    __syncthreads();  // merge reads done before region reuse
  };
  EPI(qb1, o1, m1, l1);
  EPI(qb0, o0, m0, l0);
}

// ---------------------------------------------------------------------------
extern "C" void kernel_launch(void* const* d_in, const int* in_sizes, int n_in,
                              void* d_out, int out_size, void* d_ws, size_t ws_size,
                              hipStream_t stream) {
  const float* x = (const float*)d_in[0];
  const float* Wq = (const float*)d_in[1];
  const float* Wk = (const float*)d_in[2];
  const float* Wv = (const float*)d_in[3];
  float* out = (float*)d_out;

  char* ws = (char*)d_ws;
  unsigned short* Wt = (unsigned short*)(ws);                          // 384 KB
  unsigned short* qws = (unsigned short*)(ws + 393216);                // 2 MB
  unsigned short* kws = (unsigned short*)(ws + 393216 + 2097152);      // 2 MB
  unsigned short* vtws = (unsigned short*)(ws + 393216 + 2 * 2097152); // 2 MB

  prep_w<<<dim3(48), dim3(256), 0, stream>>>(Wq, Wk, Wv, Wt);
  proj_qkv<<<dim3(512), dim3(256), 0, stream>>>(x, Wt, qws, kws, vtws);
  attn_fwd<<<dim3(256), dim3(512), 0, stream>>>(qws, kws, vtws, out);
}